// Round 1
// baseline (560.617 us; speedup 1.0000x reference)
//
#include <hip/hip_runtime.h>
#include <math.h>

#define HH 96
#define WW 320
#define CC 64
#define BB 4
#define NP 8

struct ShiftInfo {
    int   s0[NP];
    float wa[NP];    // 1 - frac
    float wb[NP];    // frac
    int   rows[2*NP];
};

// ---------------------------------------------------------------------------
// conv_ext: Cext[b][co][r-1][x] = conv3x3_SAME(zero-extended X)[r], r in [1,96]
// grid (10 xtiles, 24 rtiles, B), block 256
// ---------------------------------------------------------------------------
__global__ __launch_bounds__(256) void conv_ext_kernel(
    const float* __restrict__ X, const float* __restrict__ Wk,
    float* __restrict__ C)
{
    __shared__ float Xs[CC * 6 * 34];   // 52.2 KB
    const int xt  = blockIdx.x;
    const int rt  = blockIdx.y;
    const int b   = blockIdx.z;
    const int x0  = xt * 32;
    const int r0  = 1 + rt * 4;         // output rows r0..r0+3
    const int tid = threadIdx.x;

    // stage input rows r0-1 .. r0+4 (6 rows), cols x0-1 .. x0+32 (34 cols)
    for (int idx = tid; idx < CC * 6 * 34; idx += 256) {
        int ci  = idx / (6 * 34);
        int rem = idx - ci * (6 * 34);
        int rr  = rem / 34;
        int cc  = rem - rr * 34;
        int gr  = r0 - 1 + rr;          // 0..97 (never negative)
        int gx  = x0 - 1 + cc;
        float v = 0.f;
        if (gr < HH && gx >= 0 && gx < WW)
            v = X[((b * CC + ci) * HH + gr) * WW + gx];
        Xs[idx] = v;
    }
    __syncthreads();

    const int xp = tid & 15;            // x-pair index
    const int cg = tid >> 4;            // 0..15 -> co base cg*4
    const int xl = xp * 2;              // local x: 0,2,..,30

    float acc[4][4][2];
#pragma unroll
    for (int j = 0; j < 4; ++j)
#pragma unroll
        for (int r = 0; r < 4; ++r) { acc[j][r][0] = 0.f; acc[j][r][1] = 0.f; }

    for (int ci = 0; ci < CC; ++ci) {
        float xv[6][4];
        const float* xsp = &Xs[ci * 204 + xl];
#pragma unroll
        for (int rr = 0; rr < 6; ++rr)
#pragma unroll
            for (int cc = 0; cc < 4; ++cc)
                xv[rr][cc] = xsp[rr * 34 + cc];

#pragma unroll
        for (int j = 0; j < 4; ++j) {
            const int co = cg * 4 + j;
            const float* wp = Wk + (co * CC + ci) * 9;
            float w0 = wp[0], w1 = wp[1], w2 = wp[2];
            float w3 = wp[3], w4 = wp[4], w5 = wp[5];
            float w6 = wp[6], w7 = wp[7], w8 = wp[8];
#pragma unroll
            for (int r = 0; r < 4; ++r) {
#pragma unroll
                for (int xx = 0; xx < 2; ++xx) {
                    float s = acc[j][r][xx];
                    s += w0 * xv[r + 0][xx + 0];
                    s += w1 * xv[r + 0][xx + 1];
                    s += w2 * xv[r + 0][xx + 2];
                    s += w3 * xv[r + 1][xx + 0];
                    s += w4 * xv[r + 1][xx + 1];
                    s += w5 * xv[r + 1][xx + 2];
                    s += w6 * xv[r + 2][xx + 0];
                    s += w7 * xv[r + 2][xx + 1];
                    s += w8 * xv[r + 2][xx + 2];
                    acc[j][r][xx] = s;
                }
            }
        }
    }

#pragma unroll
    for (int j = 0; j < 4; ++j) {
        const int co = cg * 4 + j;
#pragma unroll
        for (int r = 0; r < 4; ++r) {
            const int row = r0 + r - 1;   // 0..95
            float2 val;
            val.x = acc[j][r][0];
            val.y = acc[j][r][1];
            *(float2*)&C[((size_t)(b * CC + co) * HH + row) * WW + x0 + xl] = val;
        }
    }
}

// ---------------------------------------------------------------------------
// conv_top: T[b][co][slot][x] = (W[:,:,0,:] 1x3-conv of X row rows[slot])
// grid (4 xtiles, 16 slots, B), block 256
// ---------------------------------------------------------------------------
__global__ __launch_bounds__(256) void conv_top_kernel(
    const float* __restrict__ X, const float* __restrict__ Wk,
    float* __restrict__ T, ShiftInfo si)
{
    __shared__ float Xs[CC * 82];       // 21 KB
    const int xt   = blockIdx.x;
    const int slot = blockIdx.y;
    const int b    = blockIdx.z;
    const int x0   = xt * 80;
    const int row  = si.rows[slot];
    const int tid  = threadIdx.x;

    for (int idx = tid; idx < CC * 82; idx += 256) {
        int ci = idx / 82;
        int cc = idx - ci * 82;
        int gx = x0 - 1 + cc;
        Xs[idx] = (gx >= 0 && gx < WW) ? X[((b * CC + ci) * HH + row) * WW + gx] : 0.f;
    }
    __syncthreads();

    const int co = tid >> 2;
    const int xg = tid & 3;             // 20 x each

    float acc[20];
#pragma unroll
    for (int k = 0; k < 20; ++k) acc[k] = 0.f;

    for (int ci = 0; ci < CC; ++ci) {
        const float* wp = Wk + (co * CC + ci) * 9;
        float w0 = wp[0], w1 = wp[1], w2 = wp[2];
        const float* xsp = &Xs[ci * 82 + xg * 20];
        float xv[22];
#pragma unroll
        for (int k = 0; k < 22; ++k) xv[k] = xsp[k];
#pragma unroll
        for (int k = 0; k < 20; ++k)
            acc[k] += w0 * xv[k] + w1 * xv[k + 1] + w2 * xv[k + 2];
    }

    float* outp = T + ((size_t)(b * CC + co) * 16 + slot) * WW + x0 + xg * 20;
#pragma unroll
    for (int k = 0; k < 20; ++k) outp[k] = acc[k];
}

// ---------------------------------------------------------------------------
// blend: out[b,co,y,x] = relu(bias + max_d plane_d), plane via shifted blend
// of Cext rows, with top-row (y==0) correction from Ctop.
// grid 240 blocks x 256 threads; thread = (b,co,yseg,xquad)
// ---------------------------------------------------------------------------
__global__ __launch_bounds__(256) void blend_kernel(
    const float* __restrict__ C, const float* __restrict__ T,
    const float* __restrict__ bias, float* __restrict__ Out, ShiftInfo si)
{
    const int gid  = blockIdx.x * 256 + threadIdx.x;   // 0..61439
    const int xq   = gid % 80;
    const int t2   = gid / 80;
    const int yseg = t2 % 3;
    const int t3   = t2 / 3;
    const int co   = t3 % 64;
    const int b    = t3 / 64;

    const float* Cp = C + ((size_t)(b * CC + co) * HH) * WW + xq * 4;
    const float* Tp = T + ((size_t)(b * CC + co) * 16) * WW + xq * 4;
    float*       Op = Out + ((size_t)(b * CC + co) * HH) * WW + xq * 4;
    const float  bv = bias[co];

    const int y0 = yseg * 32;

    float4 cur[NP];
#pragma unroll
    for (int d = 0; d < NP; ++d) {
        int i0 = y0 + si.s0[d] - 1;     // >= 0 always (s0 >= 1)
        if (i0 < HH) cur[d] = *(const float4*)(Cp + (size_t)i0 * WW);
        else         cur[d] = make_float4(0.f, 0.f, 0.f, 0.f);
    }

    for (int y = y0; y < y0 + 32; ++y) {
        float mx = 0.f, my = 0.f, mz = 0.f, mw = 0.f;
#pragma unroll
        for (int d = 0; d < NP; ++d) {
            float4 v0 = cur[d];
            int i1 = y + si.s0[d];
            float4 v1;
            if (i1 < HH) v1 = *(const float4*)(Cp + (size_t)i1 * WW);
            else         v1 = make_float4(0.f, 0.f, 0.f, 0.f);
            cur[d] = v1;
            float a = si.wa[d], w = si.wb[d];
            float px, py, pz, pw;
            if (y == 0) {
                float4 T0 = *(const float4*)(Tp + (size_t)(2 * d) * WW);
                float4 T1 = *(const float4*)(Tp + (size_t)(2 * d + 1) * WW);
                px = a * (v0.x - T0.x) + w * (v1.x - T1.x);
                py = a * (v0.y - T0.y) + w * (v1.y - T1.y);
                pz = a * (v0.z - T0.z) + w * (v1.z - T1.z);
                pw = a * (v0.w - T0.w) + w * (v1.w - T1.w);
            } else {
                px = a * v0.x + w * v1.x;
                py = a * v0.y + w * v1.y;
                pz = a * v0.z + w * v1.z;
                pw = a * v0.w + w * v1.w;
            }
            if (d == 0) { mx = px; my = py; mz = pz; mw = pw; }
            else {
                mx = fmaxf(mx, px); my = fmaxf(my, py);
                mz = fmaxf(mz, pz); mw = fmaxf(mw, pw);
            }
        }
        float4 o;
        o.x = fmaxf(mx + bv, 0.f);
        o.y = fmaxf(my + bv, 0.f);
        o.z = fmaxf(mz + bv, 0.f);
        o.w = fmaxf(mw + bv, 0.f);
        *(float4*)(Op + (size_t)y * WW) = o;
    }
}

// ---------------------------------------------------------------------------
extern "C" void kernel_launch(void* const* d_in, const int* in_sizes, int n_in,
                              void* d_out, int out_size, void* d_ws, size_t ws_size,
                              hipStream_t stream) {
    const float* x  = (const float*)d_in[0];
    const float* W1 = (const float*)d_in[1];
    const float* b1 = (const float*)d_in[2];
    const float* W2 = (const float*)d_in[3];
    const float* b2 = (const float*)d_in[4];
    float* out = (float*)d_out;

    float* C = (float*)d_ws;                       // 4*64*96*320 fp32 = 31.5 MB
    float* T = C + (size_t)BB * CC * HH * WW;      // 4*64*16*320 fp32 = 5.2 MB

    ShiftInfo si;
    for (int d = 0; d < NP; ++d) {
        double disp = 0.02 + d * (0.98 / 7.0);
        double sh   = 76.0 * disp;
        int s0      = (int)floor(sh);
        double w    = sh - (double)s0;
        si.s0[d] = s0;
        si.wa[d] = (float)(1.0 - w);
        si.wb[d] = (float)w;
        si.rows[2 * d]     = s0 - 1;
        si.rows[2 * d + 1] = s0;
    }

    dim3 gA(10, 24, BB);
    dim3 gT(4, 16, BB);

    // layer 1: X -> (Cext,Ctop) -> out (used as intermediate)
    conv_ext_kernel<<<gA, 256, 0, stream>>>(x, W1, C);
    conv_top_kernel<<<gT, 256, 0, stream>>>(x, W1, T, si);
    blend_kernel<<<240, 256, 0, stream>>>(C, T, b1, out, si);

    // layer 2: out -> (Cext,Ctop) -> out
    conv_ext_kernel<<<gA, 256, 0, stream>>>(out, W2, C);
    conv_top_kernel<<<gT, 256, 0, stream>>>(out, W2, T, si);
    blend_kernel<<<240, 256, 0, stream>>>(C, T, b2, out, si);
}

// Round 2
// 235.975 us; speedup vs baseline: 2.3757x; 2.3757x over previous
//
#include <hip/hip_runtime.h>
#include <math.h>

#define HH 96
#define WW 320
#define NP 8

typedef _Float16 half8_t  __attribute__((ext_vector_type(8)));
typedef _Float16 half4_t  __attribute__((ext_vector_type(4)));
typedef float    floatx16 __attribute__((ext_vector_type(16)));

struct ShiftInfo {
    int   s0[NP];
    float wa[NP];
    float wb[NP];
    int   rows[16];
};

// ---------------------------------------------------------------------------
// weights fp32 [co][ci][3][3] -> f16 [pos][co][ci], pos = ky*3+kx, both layers
// ---------------------------------------------------------------------------
__global__ __launch_bounds__(256) void wconv_kernel(
    const float* __restrict__ W1, const float* __restrict__ W2,
    _Float16* __restrict__ Wf)
{
    const float* Ws = blockIdx.x ? W2 : W1;
    _Float16* Wd = Wf + blockIdx.x * (9 * 64 * 64);
    for (int idx = threadIdx.x; idx < 9 * 64 * 64; idx += 256) {
        int pos = idx >> 12;
        int co  = (idx >> 6) & 63;
        int ci  = idx & 63;
        Wd[idx] = (_Float16)Ws[(co * 64 + ci) * 9 + pos];
    }
}

// ---------------------------------------------------------------------------
// x fp32 [b][ci][y][x] -> Xt f16 [b][y][x][ci]   (block = one (b,y) row)
// ---------------------------------------------------------------------------
__global__ __launch_bounds__(256) void xcvt_kernel(
    const float* __restrict__ X, _Float16* __restrict__ Xt)
{
    __shared__ __align__(16) _Float16 Ls[64 * 324];   // pad 320->324 (8B-align + bank spread)
    const int y = blockIdx.x, b = blockIdx.y, t = threadIdx.x;
    for (int u = t; u < 64 * 80; u += 256) {
        int ci = u / 80;
        int x4 = (u - ci * 80) * 4;
        float4 v = *(const float4*)&X[((b * 64 + ci) * HH + y) * WW + x4];
        half4_t hv = { (_Float16)v.x, (_Float16)v.y, (_Float16)v.z, (_Float16)v.w };
        *(half4_t*)&Ls[ci * 324 + x4] = hv;
    }
    __syncthreads();
    for (int idx = t; idx < 64 * WW; idx += 256) {
        int ci = idx & 63, x = idx >> 6;
        Xt[((b * HH + y) * WW + x) * 64 + ci] = Ls[ci * 324 + x];
    }
}

// ---------------------------------------------------------------------------
// MFMA implicit-GEMM conv.
// MODE==1: D[m=x][n=co] -> Out[b][OH][320][64]   (co-contiguous, for blend1)
// MODE==2: D[m=co][n=x] -> Out[b][64][OH][320]   (x-contiguous, for blend2)
// TOP: 1x3 top-row conv at 16 shift rows (OH=16), else full 3x3 ext conv (OH=96)
// block: 4 waves; wave w = one output row; tile 64 x * 64 co per row.
// ---------------------------------------------------------------------------
template<int MODE, bool TOP>
__global__ __launch_bounds__(256, 2) void conv_kernel(
    const _Float16* __restrict__ Xt, const _Float16* __restrict__ Wf,
    _Float16* __restrict__ Out, ShiftInfo si)
{
    constexpr int RS = TOP ? 4 : 6;
    __shared__ __align__(16) _Float16 Xs[RS * 66 * 72];   // [row][x(66)][ci pad 72]
    const int xt = blockIdx.x, rg = blockIdx.y, b = blockIdx.z;
    const int x0 = xt * 64;
    const int t  = threadIdx.x;

    for (int u = t; u < RS * 66 * 8; u += 256) {
        int row = u / (66 * 8);
        int rem = u - row * (66 * 8);
        int x = rem >> 3, c8 = rem & 7;
        int grow = TOP ? si.rows[rg * 4 + row] : rg * 4 + row;
        int gx = x0 - 1 + x;
        float4 v = make_float4(0.f, 0.f, 0.f, 0.f);
        if (grow < HH && gx >= 0 && gx < WW)
            v = *(const float4*)&Xt[((b * HH + grow) * WW + gx) * 64 + c8 * 8];
        *(float4*)&Xs[(row * 66 + x) * 72 + c8 * 8] = v;
    }
    __syncthreads();

    const int l = t & 63, w = t >> 6;
    const int i31 = l & 31, h = l >> 5;
    const _Float16* xb  = &Xs[(w * 66 + i31) * 72 + h * 8];
    const _Float16* wbp = &Wf[i31 * 64 + h * 8];

    floatx16 acc[2][2];
#pragma unroll
    for (int a = 0; a < 2; ++a)
#pragma unroll
        for (int c = 0; c < 2; ++c)
            acc[a][c] = (floatx16){0.f,0.f,0.f,0.f, 0.f,0.f,0.f,0.f,
                                   0.f,0.f,0.f,0.f, 0.f,0.f,0.f,0.f};

    constexpr int NPOS = TOP ? 3 : 9;
#pragma unroll
    for (int pos = 0; pos < NPOS; ++pos) {
        const int ky = TOP ? 0 : pos / 3;
        const int kx = TOP ? pos : pos - ky * 3;
#pragma unroll
        for (int ks = 0; ks < 4; ++ks) {
            half8_t wfr[2], xfr[2];
#pragma unroll
            for (int mt = 0; mt < 2; ++mt)
                wfr[mt] = *(const half8_t*)(wbp + (pos * 64 + mt * 32) * 64 + ks * 16);
#pragma unroll
            for (int nt = 0; nt < 2; ++nt)
                xfr[nt] = *(const half8_t*)(xb + (ky * 66 + kx + nt * 32) * 72 + ks * 16);
#pragma unroll
            for (int a = 0; a < 2; ++a)
#pragma unroll
                for (int c = 0; c < 2; ++c) {
                    if (MODE == 1)
                        acc[a][c] = __builtin_amdgcn_mfma_f32_32x32x16_f16(
                            xfr[a], wfr[c], acc[a][c], 0, 0, 0);
                    else
                        acc[a][c] = __builtin_amdgcn_mfma_f32_32x32x16_f16(
                            wfr[a], xfr[c], acc[a][c], 0, 0, 0);
                }
        }
    }

    constexpr int OH = TOP ? 16 : HH;
    const int om = rg * 4 + w;
#pragma unroll
    for (int a = 0; a < 2; ++a)
#pragma unroll
        for (int c = 0; c < 2; ++c)
#pragma unroll
            for (int r = 0; r < 16; ++r) {
                int dm = (r & 3) + 8 * (r >> 2) + 4 * h;   // measured 32x32 C/D row map
                if (MODE == 1) {
                    int x  = x0 + a * 32 + dm;
                    int co = c * 32 + i31;
                    Out[((b * OH + om) * WW + x) * 64 + co] = (_Float16)acc[a][c][r];
                } else {
                    int co = a * 32 + dm;
                    int x  = x0 + c * 32 + i31;
                    Out[((b * 64 + co) * OH + om) * WW + x] = (_Float16)acc[a][c][r];
                }
            }
}

// ---------------------------------------------------------------------------
// blend1: Cb1[b][96][320][64], T1[b][16][320][64] -> Xt2[b][96][320][64] f16
// block = (xt of 4 x, b); stages full column of all co.
// ---------------------------------------------------------------------------
__global__ __launch_bounds__(256) void blend1_kernel(
    const _Float16* __restrict__ Cb, const _Float16* __restrict__ T,
    const float* __restrict__ bias, _Float16* __restrict__ Xt2, ShiftInfo si)
{
    __shared__ __align__(16) _Float16 Cs[96 * 4 * 64];
    __shared__ __align__(16) _Float16 Ts[16 * 4 * 64];
    const int xt = blockIdx.x, b = blockIdx.y, t = threadIdx.x;
    const int x0 = xt * 4;

    for (int u = t; u < 96 * 4 * 8; u += 256) {
        int row = u >> 5; int rem = u & 31; int xl = rem >> 3; int c8 = rem & 7;
        *(float4*)&Cs[(row * 4 + xl) * 64 + c8 * 8] =
            *(const float4*)&Cb[((b * HH + row) * WW + x0 + xl) * 64 + c8 * 8];
    }
    for (int u = t; u < 16 * 4 * 8; u += 256) {
        int row = u >> 5; int rem = u & 31; int xl = rem >> 3; int c8 = rem & 7;
        *(float4*)&Ts[(row * 4 + xl) * 64 + c8 * 8] =
            *(const float4*)&T[((b * 16 + row) * WW + x0 + xl) * 64 + c8 * 8];
    }
    __syncthreads();

    const int co4 = t & 15, xl = (t >> 4) & 3, yt = t >> 6;
    const float4 bq = *(const float4*)&bias[co4 * 4];
    const float bvv[4] = { bq.x, bq.y, bq.z, bq.w };

    for (int it = 0; it < 24; ++it) {
        int y = yt + 4 * it;
        float mx[4];
#pragma unroll
        for (int d = 0; d < NP; ++d) {
            int r0 = y + si.s0[d] - 1;
            int r1 = r0 + 1;
            float v0[4] = {0.f,0.f,0.f,0.f}, v1[4] = {0.f,0.f,0.f,0.f};
            if (r0 < HH) {
                half4_t hv = *(const half4_t*)&Cs[(r0 * 4 + xl) * 64 + co4 * 4];
                v0[0]=hv[0]; v0[1]=hv[1]; v0[2]=hv[2]; v0[3]=hv[3];
            }
            if (r1 < HH) {
                half4_t hv = *(const half4_t*)&Cs[(r1 * 4 + xl) * 64 + co4 * 4];
                v1[0]=hv[0]; v1[1]=hv[1]; v1[2]=hv[2]; v1[3]=hv[3];
            }
            if (y == 0) {
                half4_t t0 = *(const half4_t*)&Ts[((2*d  ) * 4 + xl) * 64 + co4 * 4];
                half4_t t1 = *(const half4_t*)&Ts[((2*d+1) * 4 + xl) * 64 + co4 * 4];
#pragma unroll
                for (int j = 0; j < 4; ++j) { v0[j] -= (float)t0[j]; v1[j] -= (float)t1[j]; }
            }
            float a = si.wa[d], wgt = si.wb[d];
#pragma unroll
            for (int j = 0; j < 4; ++j) {
                float p = a * v0[j] + wgt * v1[j];
                mx[j] = (d == 0) ? p : fmaxf(mx[j], p);
            }
        }
        half4_t o;
#pragma unroll
        for (int j = 0; j < 4; ++j)
            o[j] = (_Float16)fmaxf(mx[j] + bvv[j], 0.f);
        *(half4_t*)&Xt2[((b * HH + y) * WW + x0 + xl) * 64 + co4 * 4] = o;
    }
}

// ---------------------------------------------------------------------------
// blend2: Cb2[b][64][96][320], T2[b][64][16][320] -> Out fp32 [b][64][96][320]
// block = (xt of 64 x, co, b)
// ---------------------------------------------------------------------------
__global__ __launch_bounds__(256) void blend2_kernel(
    const _Float16* __restrict__ Cb, const _Float16* __restrict__ T,
    const float* __restrict__ bias, float* __restrict__ Out, ShiftInfo si)
{
    __shared__ __align__(16) _Float16 Cs[96 * 72];
    __shared__ __align__(16) _Float16 Ts[16 * 72];
    const int xt = blockIdx.x, co = blockIdx.y, b = blockIdx.z, t = threadIdx.x;
    const int x0 = xt * 64;

    for (int u = t; u < 96 * 8; u += 256) {
        int row = u >> 3, x8 = u & 7;
        *(float4*)&Cs[row * 72 + x8 * 8] =
            *(const float4*)&Cb[((b * 64 + co) * HH + row) * WW + x0 + x8 * 8];
    }
    for (int u = t; u < 16 * 8; u += 256) {
        int row = u >> 3, x8 = u & 7;
        *(float4*)&Ts[row * 72 + x8 * 8] =
            *(const float4*)&T[((b * 64 + co) * 16 + row) * WW + x0 + x8 * 8];
    }
    __syncthreads();

    const int xq = t & 15, yt = t >> 4;
    const float bv = bias[co];

    for (int it = 0; it < 6; ++it) {
        int y = yt + 16 * it;
        float mx[4];
#pragma unroll
        for (int d = 0; d < NP; ++d) {
            int r0 = y + si.s0[d] - 1;
            int r1 = r0 + 1;
            float v0[4] = {0.f,0.f,0.f,0.f}, v1[4] = {0.f,0.f,0.f,0.f};
            if (r0 < HH) {
                half4_t hv = *(const half4_t*)&Cs[r0 * 72 + xq * 4];
                v0[0]=hv[0]; v0[1]=hv[1]; v0[2]=hv[2]; v0[3]=hv[3];
            }
            if (r1 < HH) {
                half4_t hv = *(const half4_t*)&Cs[r1 * 72 + xq * 4];
                v1[0]=hv[0]; v1[1]=hv[1]; v1[2]=hv[2]; v1[3]=hv[3];
            }
            if (y == 0) {
                half4_t t0 = *(const half4_t*)&Ts[(2*d  ) * 72 + xq * 4];
                half4_t t1 = *(const half4_t*)&Ts[(2*d+1) * 72 + xq * 4];
#pragma unroll
                for (int j = 0; j < 4; ++j) { v0[j] -= (float)t0[j]; v1[j] -= (float)t1[j]; }
            }
            float a = si.wa[d], wgt = si.wb[d];
#pragma unroll
            for (int j = 0; j < 4; ++j) {
                float p = a * v0[j] + wgt * v1[j];
                mx[j] = (d == 0) ? p : fmaxf(mx[j], p);
            }
        }
        float4 o;
        o.x = fmaxf(mx[0] + bv, 0.f);
        o.y = fmaxf(mx[1] + bv, 0.f);
        o.z = fmaxf(mx[2] + bv, 0.f);
        o.w = fmaxf(mx[3] + bv, 0.f);
        *(float4*)&Out[((b * 64 + co) * HH + y) * WW + x0 + xq * 4] = o;
    }
}

// ---------------------------------------------------------------------------
extern "C" void kernel_launch(void* const* d_in, const int* in_sizes, int n_in,
                              void* d_out, int out_size, void* d_ws, size_t ws_size,
                              hipStream_t stream) {
    const float* x  = (const float*)d_in[0];
    const float* W1 = (const float*)d_in[1];
    const float* b1 = (const float*)d_in[2];
    const float* W2 = (const float*)d_in[3];
    const float* b2 = (const float*)d_in[4];
    float* out = (float*)d_out;

    _Float16* Xt1 = (_Float16*)d_ws;            // 7,864,320 halves
    _Float16* Cb  = Xt1 + 7864320;              // 7,864,320
    _Float16* T   = Cb  + 7864320;              // 1,310,720
    _Float16* Wf  = T   + 1310720;              // 73,728 (both layers)
    _Float16* Xt2 = (_Float16*)d_out;           // scratch in d_out (overwritten by blend2)

    ShiftInfo si;
    for (int d = 0; d < NP; ++d) {
        double disp = 0.02 + d * (0.98 / 7.0);
        double sh   = 76.0 * disp;
        int s0      = (int)floor(sh);
        double w    = sh - (double)s0;
        si.s0[d] = s0;
        si.wa[d] = (float)(1.0 - w);
        si.wb[d] = (float)w;
        si.rows[2 * d]     = s0 - 1;
        si.rows[2 * d + 1] = s0;
    }

    wconv_kernel<<<dim3(2), 256, 0, stream>>>(W1, W2, Wf);
    xcvt_kernel<<<dim3(HH, 4), 256, 0, stream>>>(x, Xt1);

    // layer 1 (transposed-output mode)
    conv_kernel<1, false><<<dim3(5, 24, 4), 256, 0, stream>>>(Xt1, Wf, Cb, si);
    conv_kernel<1, true ><<<dim3(5, 4, 4), 256, 0, stream>>>(Xt1, Wf, T, si);
    blend1_kernel<<<dim3(80, 4), 256, 0, stream>>>(Cb, T, b1, Xt2, si);

    // layer 2 (natural-output mode)
    conv_kernel<2, false><<<dim3(5, 24, 4), 256, 0, stream>>>(Xt2, Wf + 36864, Cb, si);
    conv_kernel<2, true ><<<dim3(5, 4, 4), 256, 0, stream>>>(Xt2, Wf + 36864, T, si);
    blend2_kernel<<<dim3(5, 64, 4), 256, 0, stream>>>(Cb, T, b2, out, si);
}

// Round 3
// 224.010 us; speedup vs baseline: 2.5026x; 1.0534x over previous
//
#include <hip/hip_runtime.h>
#include <math.h>

#define HH 96
#define WW 320
#define NP 8

typedef _Float16 half8_t  __attribute__((ext_vector_type(8)));
typedef _Float16 half4_t  __attribute__((ext_vector_type(4)));
typedef float    floatx16 __attribute__((ext_vector_type(16)));

struct ShiftInfo {
    int   s0[NP];
    float wa[NP];
    float wb[NP];
    int   rows[16];
};

// ---------------------------------------------------------------------------
// prep: blockIdx.x < 96 -> transpose+cvt one (b,y) row of X into Xt f16
//       blockIdx.x >= 96 (b==0 only) -> weight cvt [co][ci][3][3] -> [pos][co][ci]
// ---------------------------------------------------------------------------
__global__ __launch_bounds__(256) void prep_kernel(
    const float* __restrict__ X, const float* __restrict__ W1,
    const float* __restrict__ W2, _Float16* __restrict__ Xt,
    _Float16* __restrict__ Wf)
{
    const int bx = blockIdx.x, b = blockIdx.y, t = threadIdx.x;
    if (bx < HH) {
        __shared__ __align__(16) _Float16 Ls[64 * 324];
        const int y = bx;
        for (int u = t; u < 64 * 80; u += 256) {
            int ci = u / 80;
            int x4 = (u - ci * 80) * 4;
            float4 v = *(const float4*)&X[((b * 64 + ci) * HH + y) * WW + x4];
            half4_t hv = { (_Float16)v.x, (_Float16)v.y, (_Float16)v.z, (_Float16)v.w };
            *(half4_t*)&Ls[ci * 324 + x4] = hv;
        }
        __syncthreads();
        const int ci8 = t & 7, xg = t >> 3;
        for (int it = 0; it < 10; ++it) {
            int x = xg + 32 * it;
            half8_t o;
#pragma unroll
            for (int j = 0; j < 8; ++j) o[j] = Ls[(ci8 * 8 + j) * 324 + x];
            *(half8_t*)&Xt[((size_t)(b * HH + y) * WW + x) * 64 + ci8 * 8] = o;
        }
    } else if (b == 0) {
        const int k = bx - HH;              // 0..17
        const int layer = k / 9, pos = k - layer * 9;
        const float* Ws = layer ? W2 : W1;
        _Float16* Wd = Wf + layer * (9 * 64 * 64) + pos * 64 * 64;
        for (int u = t; u < 4096; u += 256) {
            int co = u >> 6, ci = u & 63;
            Wd[u] = (_Float16)Ws[(co * 64 + ci) * 9 + pos];
        }
    }
}

// ---------------------------------------------------------------------------
// MFMA implicit-GEMM conv, ext + top merged.
// blockIdx.y in [0,24): ext conv rows, output OutE (OH=96)
// blockIdx.y in [24,28): top 1x3 conv at 16 shift rows, output OutT (OH=16)
// MODE==1: D[m=x][n=co] -> [b][OH][320][64]; MODE==2: D[m=co][n=x] -> [b][64][OH][320]
// ---------------------------------------------------------------------------
template<int MODE>
__global__ __launch_bounds__(256, 2) void conv_kernel(
    const _Float16* __restrict__ Xt, const _Float16* __restrict__ Wf,
    _Float16* __restrict__ OutE, _Float16* __restrict__ OutT, ShiftInfo si)
{
    __shared__ __align__(16) _Float16 Xs[6 * 66 * 72];
    const int xt = blockIdx.x, rg = blockIdx.y, b = blockIdx.z;
    const bool top = rg >= 24;
    const int trg = rg - 24;
    const int x0 = xt * 64;
    const int t  = threadIdx.x;

    for (int u = t; u < 6 * 66 * 8; u += 256) {
        int row = u / (66 * 8);
        int rem = u - row * (66 * 8);
        int x = rem >> 3, c8 = rem & 7;
        int grow = top ? ((row < 4) ? si.rows[trg * 4 + row] : -1) : rg * 4 + row;
        int gx = x0 - 1 + x;
        float4 v = make_float4(0.f, 0.f, 0.f, 0.f);
        if ((unsigned)grow < HH && gx >= 0 && gx < WW)
            v = *(const float4*)&Xt[((size_t)(b * HH + grow) * WW + gx) * 64 + c8 * 8];
        *(float4*)&Xs[(row * 66 + x) * 72 + c8 * 8] = v;
    }
    __syncthreads();

    const int l = t & 63, w = t >> 6;
    const int i31 = l & 31, h = l >> 5;
    const _Float16* xb  = &Xs[(w * 66 + i31) * 72 + h * 8];
    const _Float16* wbp = &Wf[i31 * 64 + h * 8];

    floatx16 acc[2][2];
#pragma unroll
    for (int a = 0; a < 2; ++a)
#pragma unroll
        for (int c = 0; c < 2; ++c)
            acc[a][c] = (floatx16){0.f,0.f,0.f,0.f, 0.f,0.f,0.f,0.f,
                                   0.f,0.f,0.f,0.f, 0.f,0.f,0.f,0.f};

    const int npos = top ? 3 : 9;
#pragma unroll
    for (int pos = 0; pos < 9; ++pos) {
        if (pos >= npos) break;
        const int ky = pos / 3;
        const int kx = pos - ky * 3;
#pragma unroll
        for (int ks = 0; ks < 4; ++ks) {
            half8_t wfr[2], xfr[2];
#pragma unroll
            for (int mt = 0; mt < 2; ++mt)
                wfr[mt] = *(const half8_t*)(wbp + (pos * 64 + mt * 32) * 64 + ks * 16);
#pragma unroll
            for (int nt = 0; nt < 2; ++nt)
                xfr[nt] = *(const half8_t*)(xb + (ky * 66 + kx + nt * 32) * 72 + ks * 16);
#pragma unroll
            for (int a = 0; a < 2; ++a)
#pragma unroll
                for (int c = 0; c < 2; ++c) {
                    if (MODE == 1)
                        acc[a][c] = __builtin_amdgcn_mfma_f32_32x32x16_f16(
                            xfr[a], wfr[c], acc[a][c], 0, 0, 0);
                    else
                        acc[a][c] = __builtin_amdgcn_mfma_f32_32x32x16_f16(
                            wfr[a], xfr[c], acc[a][c], 0, 0, 0);
                }
        }
    }

    const int OH = top ? 16 : HH;
    const int om = top ? (trg * 4 + w) : (rg * 4 + w);
    _Float16* Out = top ? OutT : OutE;
#pragma unroll
    for (int a = 0; a < 2; ++a)
#pragma unroll
        for (int c = 0; c < 2; ++c)
#pragma unroll
            for (int r = 0; r < 16; ++r) {
                int dm = (r & 3) + 8 * (r >> 2) + 4 * h;
                if (MODE == 1) {
                    int x  = x0 + a * 32 + dm;
                    int co = c * 32 + i31;
                    Out[((size_t)(b * OH + om) * WW + x) * 64 + co] = (_Float16)acc[a][c][r];
                } else {
                    int co = a * 32 + dm;
                    int x  = x0 + c * 32 + i31;
                    Out[((size_t)(b * 64 + co) * OH + om) * WW + x] = (_Float16)acc[a][c][r];
                }
            }
}

// ---------------------------------------------------------------------------
// blend1: C[b][96][320][64] + T[b][16][320][64] -> Xt2[b][96][320][64] (f16)
// no LDS: rolling-register row reuse, packed-f16 math.
// grid (10 xchunks, 12 ysegs, 4 b), block 256 = 8 co8 x 32 x
// ---------------------------------------------------------------------------
__global__ __launch_bounds__(256) void blend1_kernel(
    const _Float16* __restrict__ C, const _Float16* __restrict__ T,
    const float* __restrict__ bias, _Float16* __restrict__ Xt2, ShiftInfo si)
{
    const int t = threadIdx.x;
    const int co8 = t & 7, xl = t >> 3;
    const int x = blockIdx.x * 32 + xl;
    const int y0 = blockIdx.y * 8;
    const int b = blockIdx.z;

    const _Float16* Cp = C + ((size_t)(b * HH) * WW + x) * 64 + co8 * 8;
    const half8_t z = {0,0,0,0,0,0,0,0};

    half8_t cur[NP];
#pragma unroll
    for (int d = 0; d < NP; ++d) {
        int r = y0 + si.s0[d] - 1;
        cur[d] = (r < HH) ? *(const half8_t*)(Cp + (size_t)r * WW * 64) : z;
    }
    half8_t bv;
#pragma unroll
    for (int j = 0; j < 8; ++j) bv[j] = (_Float16)bias[co8 * 8 + j];

    for (int y = y0; y < y0 + 8; ++y) {
        half8_t m = z;
#pragma unroll
        for (int d = 0; d < NP; ++d) {
            int r1 = y + si.s0[d];
            half8_t v1 = (r1 < HH) ? *(const half8_t*)(Cp + (size_t)r1 * WW * 64) : z;
            half8_t v0 = cur[d];
            cur[d] = v1;
            _Float16 a = (_Float16)si.wa[d], wg = (_Float16)si.wb[d];
            half8_t p;
            if (y == 0) {
                const _Float16* Tp = T + ((size_t)(b * 16) * WW + x) * 64 + co8 * 8;
                half8_t t0 = *(const half8_t*)(Tp + (size_t)(2 * d) * WW * 64);
                half8_t t1 = *(const half8_t*)(Tp + (size_t)(2 * d + 1) * WW * 64);
                p = a * (v0 - t0) + wg * (v1 - t1);
            } else {
                p = a * v0 + wg * v1;
            }
            m = (d == 0) ? p : __builtin_elementwise_max(m, p);
        }
        half8_t o = __builtin_elementwise_max(m + bv, z);
        *(half8_t*)&Xt2[((size_t)(b * HH + y) * WW + x) * 64 + co8 * 8] = o;
    }
}

// ---------------------------------------------------------------------------
// blend2: C[b][64][96][320] + T[b][64][16][320] -> Out fp32 [b][64][96][320]
// grid (5 xt, 16 = 2 cohalf x 8 yseg, 4 b), block 256 = 8 x8 x 32 co
// ---------------------------------------------------------------------------
__global__ __launch_bounds__(256) void blend2_kernel(
    const _Float16* __restrict__ C, const _Float16* __restrict__ T,
    const float* __restrict__ bias, float* __restrict__ Out, ShiftInfo si)
{
    const int t = threadIdx.x;
    const int x8 = t & 7, col = t >> 3;
    const int cb = blockIdx.y & 1, ys = blockIdx.y >> 1;
    const int b = blockIdx.z;
    const int co = cb * 32 + col;
    const int x = blockIdx.x * 64 + x8 * 8;
    const int y0 = ys * 12;

    const _Float16* Cp = C + ((size_t)(b * 64 + co) * HH) * WW + x;
    const _Float16* Tp = T + ((size_t)(b * 64 + co) * 16) * WW + x;
    const float bvf = bias[co];
    const half8_t z = {0,0,0,0,0,0,0,0};

    half8_t cur[NP];
#pragma unroll
    for (int d = 0; d < NP; ++d) {
        int r = y0 + si.s0[d] - 1;
        cur[d] = (r < HH) ? *(const half8_t*)(Cp + (size_t)r * WW) : z;
    }

    for (int y = y0; y < y0 + 12; ++y) {
        half8_t m = z;
#pragma unroll
        for (int d = 0; d < NP; ++d) {
            int r1 = y + si.s0[d];
            half8_t v1 = (r1 < HH) ? *(const half8_t*)(Cp + (size_t)r1 * WW) : z;
            half8_t v0 = cur[d];
            cur[d] = v1;
            _Float16 a = (_Float16)si.wa[d], wg = (_Float16)si.wb[d];
            half8_t p;
            if (y == 0) {
                half8_t t0 = *(const half8_t*)(Tp + (size_t)(2 * d) * WW);
                half8_t t1 = *(const half8_t*)(Tp + (size_t)(2 * d + 1) * WW);
                p = a * (v0 - t0) + wg * (v1 - t1);
            } else {
                p = a * v0 + wg * v1;
            }
            m = (d == 0) ? p : __builtin_elementwise_max(m, p);
        }
        float4 o0, o1;
        o0.x = fmaxf((float)m[0] + bvf, 0.f);
        o0.y = fmaxf((float)m[1] + bvf, 0.f);
        o0.z = fmaxf((float)m[2] + bvf, 0.f);
        o0.w = fmaxf((float)m[3] + bvf, 0.f);
        o1.x = fmaxf((float)m[4] + bvf, 0.f);
        o1.y = fmaxf((float)m[5] + bvf, 0.f);
        o1.z = fmaxf((float)m[6] + bvf, 0.f);
        o1.w = fmaxf((float)m[7] + bvf, 0.f);
        float* op = Out + ((size_t)(b * 64 + co) * HH + y) * WW + x;
        *(float4*)op = o0;
        *(float4*)(op + 4) = o1;
    }
}

// ---------------------------------------------------------------------------
extern "C" void kernel_launch(void* const* d_in, const int* in_sizes, int n_in,
                              void* d_out, int out_size, void* d_ws, size_t ws_size,
                              hipStream_t stream) {
    const float* x  = (const float*)d_in[0];
    const float* W1 = (const float*)d_in[1];
    const float* b1 = (const float*)d_in[2];
    const float* W2 = (const float*)d_in[3];
    const float* b2 = (const float*)d_in[4];
    float* out = (float*)d_out;

    _Float16* Xt1 = (_Float16*)d_ws;            // 7,864,320 halves
    _Float16* Cb  = Xt1 + 7864320;              // 7,864,320
    _Float16* T   = Cb  + 7864320;              // 1,310,720
    _Float16* Wf  = T   + 1310720;              // 73,728 (both layers)
    _Float16* Xt2 = (_Float16*)d_out;           // f16 scratch inside d_out

    ShiftInfo si;
    for (int d = 0; d < NP; ++d) {
        double disp = 0.02 + d * (0.98 / 7.0);
        double sh   = 76.0 * disp;
        int s0      = (int)floor(sh);
        double w    = sh - (double)s0;
        si.s0[d] = s0;
        si.wa[d] = (float)(1.0 - w);
        si.wb[d] = (float)w;
        si.rows[2 * d]     = s0 - 1;
        si.rows[2 * d + 1] = s0;
    }

    prep_kernel<<<dim3(HH + 18, 4), 256, 0, stream>>>(x, W1, W2, Xt1, Wf);

    conv_kernel<1><<<dim3(5, 28, 4), 256, 0, stream>>>(Xt1, Wf, Cb, T, si);
    blend1_kernel<<<dim3(10, 12, 4), 256, 0, stream>>>(Cb, T, b1, Xt2, si);

    conv_kernel<2><<<dim3(5, 28, 4), 256, 0, stream>>>(Xt2, Wf + 36864, Cb, T, si);
    blend2_kernel<<<dim3(5, 16, 4), 256, 0, stream>>>(Cb, T, b2, out, si);
}